// Round 8
// baseline (171.505 us; speedup 1.0000x reference)
//
#include <hip/hip_runtime.h>
#include <hip/hip_bf16.h>
#include <stdint.h>

namespace {

constexpr int L = 8192;
constexpr int D = 256;

// K1: levels 0..5 (dilation 1..32). Block 512 thr = 8 waves, 32-channel tile,
// 256 staged t (64 halo + 192 valid). Lane owns 4 t of each of 4 channels.
constexpr int K1_CT  = 32;
constexpr int K1_OUT = 192;
constexpr int K1_S   = 270;   // words/row; even (b64 align), mod 32 = 14 (bank spread)

// K2: levels 6..12 (t1-dilation 1..64). Block 512 thr, 32-ch x 2-t2 tile,
// t1 range 128. Lane owns t1 {2l, 2l+1} of each of 8 rows.
constexpr int K2_CT = 32;
constexpr int K2_T2 = 2;
constexpr int K2_S  = 134;    // words/row; even, mod 32 = 6

// quad-preserving swizzle: consecutive p stay consecutive within 32-block,
// even p stays even (b64 alignment), +2 jump per 32 breaks bank alignment.
__device__ __forceinline__ int phie(int p) { return p + 2 * (p >> 5); }

// pack {bf16(y1) low 16, bf16(a6) high 16}
__device__ __forceinline__ uint32_t pk2(float ylo, float ahi) {
    union { __hip_bfloat16 h; uint16_t u; } a, b;
    a.h = __float2bfloat16(ylo);
    b.h = __float2bfloat16(ahi);
    return ((uint32_t)b.u << 16) | (uint32_t)a.u;
}
__device__ __forceinline__ float up_lo(uint32_t u) { return __uint_as_float(u << 16); }
__device__ __forceinline__ float up_hi(uint32_t u) { return __uint_as_float(u & 0xffff0000u); }

// shift-up-by-1 (HW-verified ds_bpermute path). Clamp at lane 0 (k1: halo-safe).
__device__ __forceinline__ float sh1(float v) { return __shfl_up(v, 1); }
// zero-filled variant for k2 (t1 < 0 must read 0).
__device__ __forceinline__ float sh1z(float v, int lane) {
    const float s = __shfl_up(v, 1);
    return (lane >= 1) ? s : 0.f;
}

__device__ __forceinline__ void lvl4(float (&a)[4], float (&y)[4],
                                     float l0, float l1, float l2, float l3,
                                     float h00, float h01, float h10, float h11,
                                     float wj) {
    const float lk[4] = {l0, l1, l2, l3};
#pragma unroll
    for (int i = 0; i < 4; ++i) {
        const float bv = lk[i] * h10 + a[i] * h11;
        y[i] = fmaf(wj, bv, y[i]);
        a[i] = lk[i] * h00 + a[i] * h01;
    }
}

// ---------------- Kernel 1: levels 0..5 ----------------
__global__ __launch_bounds__(512, 8)
void mrl_k1(const float* __restrict__ x, const float* __restrict__ h0,
            const float* __restrict__ h1, const float* __restrict__ w,
            uint32_t* __restrict__ out_pk) {
    __shared__ uint32_t lds[K1_CT * K1_S];   // 34.6 KB
    const int tid = threadIdx.x;
    const int b  = blockIdx.z;
    const int c0 = blockIdx.y * K1_CT;
    const int t0 = blockIdx.x * K1_OUT;
    const int tsb = t0 - 64;                 // first staged t (64-t halo)

    // ---- stage x coalesced (float4 over channels) -> channel-major swizzled LDS
    {
        const int cq = (tid & 7) * 4;
        const int tr = tid >> 3;             // 0..63
        const float* xb = x + (size_t)b * L * D + c0 + cq;
#pragma unroll
        for (int it = 0; it < 4; ++it) {
            const int p = it * 64 + tr;
            const int t = tsb + p;
            float4 v = make_float4(0.f, 0.f, 0.f, 0.f);
            if (t >= 0 && t < L) v = *reinterpret_cast<const float4*>(xb + (size_t)t * D);
            const int ph = phie(p);
            lds[(cq + 0) * K1_S + ph] = __float_as_uint(v.x);
            lds[(cq + 1) * K1_S + ph] = __float_as_uint(v.y);
            lds[(cq + 2) * K1_S + ph] = __float_as_uint(v.z);
            lds[(cq + 3) * K1_S + ph] = __float_as_uint(v.w);
        }
    }
    __syncthreads();

    // ---- compute: 4 channel-chains per wave, fully interleaved in registers
    {
        const int lane = tid & 63;
        const int wv   = tid >> 6;           // 0..7
        const int p0  = 4 * lane;
        const int ph0 = phie(p0);            // even; p0..p0+3 stay contiguous

        // wave-uniform channels -> scalar (SGPR) coefficient loads
        int cu[4];
        float h00[4], h01[4], h10[4], h11[4];
#pragma unroll
        for (int u = 0; u < 4; ++u) {
            cu[u] = __builtin_amdgcn_readfirstlane(c0 + wv + 8 * u);
            h00[u] = h0[2 * cu[u]];  h01[u] = h0[2 * cu[u] + 1];
            h10[u] = h1[2 * cu[u]];  h11[u] = h1[2 * cu[u] + 1];
        }

        float A[4][4], Y[4][4];
        // read ALL chains (b64 pairs)
#pragma unroll
        for (int u = 0; u < 4; ++u) {
            const int base = (wv + 8 * u) * K1_S + ph0;
            const uint2 r0 = *reinterpret_cast<const uint2*>(&lds[base]);
            const uint2 r1 = *reinterpret_cast<const uint2*>(&lds[base + 2]);
            A[u][0] = __uint_as_float(r0.x); A[u][1] = __uint_as_float(r0.y);
            A[u][2] = __uint_as_float(r1.x); A[u][3] = __uint_as_float(r1.y);
            const float w0 = w[cu[u]];
#pragma unroll
            for (int i = 0; i < 4; ++i) Y[u][i] = w0 * A[u][i];
        }

        // d=1: look = {lane-1 a3, a0, a1, a2}
#pragma unroll
        for (int u = 0; u < 4; ++u)
            lvl4(A[u], Y[u], sh1(A[u][3]), A[u][0], A[u][1], A[u][2],
                 h00[u], h01[u], h10[u], h11[u], w[1 * D + cu[u]]);
        // d=2
#pragma unroll
        for (int u = 0; u < 4; ++u)
            lvl4(A[u], Y[u], sh1(A[u][2]), sh1(A[u][3]), A[u][0], A[u][1],
                 h00[u], h01[u], h10[u], h11[u], w[2 * D + cu[u]]);
        // d=4: full slab of lane-1
#pragma unroll
        for (int u = 0; u < 4; ++u)
            lvl4(A[u], Y[u], sh1(A[u][0]), sh1(A[u][1]), sh1(A[u][2]), sh1(A[u][3]),
                 h00[u], h01[u], h10[u], h11[u], w[3 * D + cu[u]]);
        // d=8,16,32: lane-m slabs, m=2,4,8 (clamp garbage lands in halo p<64)
#pragma unroll
        for (int u = 0; u < 4; ++u)
            lvl4(A[u], Y[u], __shfl_up(A[u][0], 2), __shfl_up(A[u][1], 2),
                 __shfl_up(A[u][2], 2), __shfl_up(A[u][3], 2),
                 h00[u], h01[u], h10[u], h11[u], w[4 * D + cu[u]]);
#pragma unroll
        for (int u = 0; u < 4; ++u)
            lvl4(A[u], Y[u], __shfl_up(A[u][0], 4), __shfl_up(A[u][1], 4),
                 __shfl_up(A[u][2], 4), __shfl_up(A[u][3], 4),
                 h00[u], h01[u], h10[u], h11[u], w[5 * D + cu[u]]);
#pragma unroll
        for (int u = 0; u < 4; ++u)
            lvl4(A[u], Y[u], __shfl_up(A[u][0], 8), __shfl_up(A[u][1], 8),
                 __shfl_up(A[u][2], 8), __shfl_up(A[u][3], 8),
                 h00[u], h01[u], h10[u], h11[u], w[6 * D + cu[u]]);

        // write ALL chains packed (b64 pairs)
#pragma unroll
        for (int u = 0; u < 4; ++u) {
            const int base = (wv + 8 * u) * K1_S + ph0;
            uint2 w0v, w1v;
            w0v.x = pk2(Y[u][0], A[u][0]); w0v.y = pk2(Y[u][1], A[u][1]);
            w1v.x = pk2(Y[u][2], A[u][2]); w1v.y = pk2(Y[u][3], A[u][3]);
            *reinterpret_cast<uint2*>(&lds[base])     = w0v;
            *reinterpret_cast<uint2*>(&lds[base + 2]) = w1v;
        }
    }
    __syncthreads();

    // ---- coalesced packed store, valid p in [64, 256)
    {
        const int cq = (tid & 7) * 4;
        const int tr = tid >> 3;             // 0..63
        uint32_t* ob = out_pk + (size_t)b * L * D + c0 + cq;
#pragma unroll
        for (int it = 0; it < 3; ++it) {
            const int p = 64 + it * 64 + tr;
            const int t = tsb + p;
            if (t < L) {
                const int ph = phie(p);
                uint4 v;
                v.x = lds[(cq + 0) * K1_S + ph];
                v.y = lds[(cq + 1) * K1_S + ph];
                v.z = lds[(cq + 2) * K1_S + ph];
                v.w = lds[(cq + 3) * K1_S + ph];
                *reinterpret_cast<uint4*>(ob + (size_t)t * D) = v;
            }
        }
    }
}

// ---------------- Kernel 2: levels 6..12 + final terms ----------------
// t = t1*64 + t2; coupling only along t1 (128 long). In-place on d_out.
__global__ __launch_bounds__(512, 8)
void mrl_k2(const float* __restrict__ h0, const float* __restrict__ h1,
            const float* __restrict__ w, float* __restrict__ y) {
    __shared__ uint32_t lds[K2_CT * K2_T2 * K2_S];   // 34.3 KB
    const int tid = threadIdx.x;
    const int b   = blockIdx.z;
    const int c0  = blockIdx.y * K2_CT;
    const int t2a = blockIdx.x * K2_T2;
    uint32_t* yb = reinterpret_cast<uint32_t*>(y) + (size_t)b * L * D + c0;

    // ---- stage packed {y1,a6} coalesced (uint4 over channels)
    {
        const int cq  = (tid & 7) * 4;
        const int t2i = (tid >> 3) & 1;
        const int t1r = tid >> 4;            // 0..31
#pragma unroll
        for (int it = 0; it < 4; ++it) {
            const int t1 = it * 32 + t1r;
            const int t  = t1 * 64 + t2a + t2i;
            const uint4 v = *reinterpret_cast<const uint4*>(yb + (size_t)t * D + cq);
            const int ph = phie(t1);
            lds[((cq + 0) * 2 + t2i) * K2_S + ph] = v.x;
            lds[((cq + 1) * 2 + t2i) * K2_S + ph] = v.y;
            lds[((cq + 2) * 2 + t2i) * K2_S + ph] = v.z;
            lds[((cq + 3) * 2 + t2i) * K2_S + ph] = v.w;
        }
    }
    __syncthreads();

    // ---- compute: 8 row-chains per wave, fully interleaved in registers
    {
        const int lane = tid & 63;
        const int wv   = tid >> 6;           // 0..7
        const int ph0  = phie(2 * lane);     // even; pair (2l, 2l+1) contiguous

        int cu[8];
        float h00[8], h01[8], h10[8], h11[8];
#pragma unroll
        for (int q = 0; q < 8; ++q) {
            cu[q] = __builtin_amdgcn_readfirstlane(c0 + ((wv + 8 * q) >> 1));
            h00[q] = h0[2 * cu[q]];  h01[q] = h0[2 * cu[q] + 1];
            h10[q] = h1[2 * cu[q]];  h11[q] = h1[2 * cu[q] + 1];
        }

        float A0[8], A1[8], Y0[8], Y1[8];
#pragma unroll
        for (int q = 0; q < 8; ++q) {
            const int base = (wv + 8 * q) * K2_S + ph0;
            const uint2 r = *reinterpret_cast<const uint2*>(&lds[base]);
            A0[q] = up_hi(r.x); Y0[q] = up_lo(r.x);
            A1[q] = up_hi(r.y); Y1[q] = up_lo(r.y);
        }

        // t1-dilation 1 (level 6): l0 = lane-1's a1 (0 at t1<0), l1 = own a0
#pragma unroll
        for (int q = 0; q < 8; ++q) {
            const float wj = w[7 * D + cu[q]];
            const float l0 = sh1z(A1[q], lane);
            const float l1 = A0[q];
            const float bv0 = l0 * h10[q] + A0[q] * h11[q];
            const float bv1 = l1 * h10[q] + A1[q] * h11[q];
            Y0[q] = fmaf(wj, bv0, Y0[q]);
            Y1[q] = fmaf(wj, bv1, Y1[q]);
            A0[q] = l0 * h00[q] + A0[q] * h01[q];
            A1[q] = l1 * h00[q] + A1[q] * h01[q];
        }
        // t1-dilation 2: lane-1 full slab (zero at lane 0 = t1<0)
#pragma unroll
        for (int q = 0; q < 8; ++q) {
            const float wj = w[8 * D + cu[q]];
            const float l0 = sh1z(A0[q], lane);
            const float l1 = sh1z(A1[q], lane);
            const float bv0 = l0 * h10[q] + A0[q] * h11[q];
            const float bv1 = l1 * h10[q] + A1[q] * h11[q];
            Y0[q] = fmaf(wj, bv0, Y0[q]);
            Y1[q] = fmaf(wj, bv1, Y1[q]);
            A0[q] = l0 * h00[q] + A0[q] * h01[q];
            A1[q] = l1 * h00[q] + A1[q] * h01[q];
        }
        // t1-dilation 4,8,16,32,64: lane-m slabs, m=2,4,8,16,32 (masked shfl)
#pragma unroll
        for (int k = 0; k < 5; ++k) {
            const int m = 2 << k;
#pragma unroll
            for (int q = 0; q < 8; ++q) {
                const float wj = w[(9 + k) * D + cu[q]];
                const float s0 = __shfl_up(A0[q], m);
                const float s1 = __shfl_up(A1[q], m);
                const bool ok = (lane >= m);
                const float l0 = ok ? s0 : 0.f;
                const float l1 = ok ? s1 : 0.f;
                const float bv0 = l0 * h10[q] + A0[q] * h11[q];
                const float bv1 = l1 * h10[q] + A1[q] * h11[q];
                Y0[q] = fmaf(wj, bv0, Y0[q]);
                Y1[q] = fmaf(wj, bv1, Y1[q]);
                A0[q] = l0 * h00[q] + A0[q] * h01[q];
                A1[q] = l1 * h00[q] + A1[q] * h01[q];
            }
        }
        // final a-term + write back
#pragma unroll
        for (int q = 0; q < 8; ++q) {
            const float w14 = w[14 * D + cu[q]];
            const int base = (wv + 8 * q) * K2_S + ph0;
            uint2 wv2;
            wv2.x = __float_as_uint(fmaf(w14, A0[q], Y0[q]));
            wv2.y = __float_as_uint(fmaf(w14, A1[q], Y1[q]));
            *reinterpret_cast<uint2*>(&lds[base]) = wv2;
        }
    }
    __syncthreads();

    // ---- coalesced final f32 store
    {
        const int cq = (tid & 7) * 4;
        const int rq = tid >> 3;             // 0..63
#pragma unroll
        for (int it = 0; it < 4; ++it) {
            const int row = it * 64 + rq;    // 0..255
            const int t1 = row >> 1, t2i = row & 1;
            const int t  = t1 * 64 + t2a + t2i;
            const int ph = phie(t1);
            uint4 v;
            v.x = lds[((cq + 0) * 2 + t2i) * K2_S + ph];
            v.y = lds[((cq + 1) * 2 + t2i) * K2_S + ph];
            v.z = lds[((cq + 2) * 2 + t2i) * K2_S + ph];
            v.w = lds[((cq + 3) * 2 + t2i) * K2_S + ph];
            *reinterpret_cast<uint4*>(yb + (size_t)t * D + cq) = v;
        }
    }
}

} // namespace

extern "C" void kernel_launch(void* const* d_in, const int* in_sizes, int n_in,
                              void* d_out, int out_size, void* d_ws, size_t ws_size,
                              hipStream_t stream) {
    const float* x  = (const float*)d_in[0];
    const float* h0 = (const float*)d_in[1];
    const float* h1 = (const float*)d_in[2];
    const float* w  = (const float*)d_in[3];
    float* y = (float*)d_out;
    (void)d_ws; (void)ws_size;

    const int B = in_sizes[0] / (L * D);   // = 8

    dim3 g1((L + K1_OUT - 1) / K1_OUT, D / K1_CT, B);  // (43, 8, 8)
    dim3 g2(64 / K2_T2, D / K2_CT, B);                 // (32, 8, 8)

    mrl_k1<<<g1, 512, 0, stream>>>(x, h0, h1, w, (uint32_t*)y);
    mrl_k2<<<g2, 512, 0, stream>>>(h0, h1, w, y);
}

// Round 9
// 161.185 us; speedup vs baseline: 1.0640x; 1.0640x over previous
//
#include <hip/hip_runtime.h>
#include <hip/hip_bf16.h>
#include <stdint.h>

namespace {

constexpr int L = 8192;
constexpr int D = 256;

// K1: levels 0..5 (dilation 1..32). Block 512 thr = 8 waves, 32-channel tile,
// 256 staged t (64 halo + 192 valid). Lane owns 4 t; wave owns 4 channel rows
// processed in 2 sequential groups of 2 (16 floats live -> no spill).
constexpr int K1_CT  = 32;
constexpr int K1_OUT = 192;
constexpr int K1_S   = 270;   // words/row; even (b64 align), mod 32 = 14

// K2: levels 6..12 (t1-dilation 1..64). Block 512 thr, 32-ch x 2-t2 tile,
// t1 range 128. Lane owns t1 {2l,2l+1}; wave owns 8 rows in 2 groups of 4.
constexpr int K2_CT = 32;
constexpr int K2_T2 = 2;
constexpr int K2_S  = 134;    // words/row; even, mod 32 = 6

// quad-preserving swizzle: consecutive p stay consecutive within 32-block,
// even p stays even (b64 alignment), +2 jump per 32 breaks bank alignment.
__device__ __forceinline__ int phie(int p) { return p + 2 * (p >> 5); }

// pack {bf16(y1) low 16, bf16(a6) high 16}
__device__ __forceinline__ uint32_t pk2(float ylo, float ahi) {
    union { __hip_bfloat16 h; uint16_t u; } a, b;
    a.h = __float2bfloat16(ylo);
    b.h = __float2bfloat16(ahi);
    return ((uint32_t)b.u << 16) | (uint32_t)a.u;
}
__device__ __forceinline__ float up_lo(uint32_t u) { return __uint_as_float(u << 16); }
__device__ __forceinline__ float up_hi(uint32_t u) { return __uint_as_float(u & 0xffff0000u); }

__device__ __forceinline__ float sh1(float v) { return __shfl_up(v, 1); }
__device__ __forceinline__ float sh1z(float v, int lane) {
    const float s = __shfl_up(v, 1);
    return (lane >= 1) ? s : 0.f;
}

__device__ __forceinline__ void lvl4(float (&a)[4], float (&y)[4],
                                     float l0, float l1, float l2, float l3,
                                     float h00, float h01, float h10, float h11,
                                     float wj) {
    const float lk[4] = {l0, l1, l2, l3};
#pragma unroll
    for (int i = 0; i < 4; ++i) {
        const float bv = lk[i] * h10 + a[i] * h11;
        y[i] = fmaf(wj, bv, y[i]);
        a[i] = lk[i] * h00 + a[i] * h01;
    }
}

// ---------------- Kernel 1: levels 0..5 ----------------
__global__ __launch_bounds__(512, 8)
void mrl_k1(const float* __restrict__ x, const float* __restrict__ h0,
            const float* __restrict__ h1, const float* __restrict__ w,
            uint32_t* __restrict__ out_pk) {
    __shared__ uint32_t lds[K1_CT * K1_S];   // 34.6 KB
    const int tid = threadIdx.x;
    const int b  = blockIdx.z;
    const int c0 = blockIdx.y * K1_CT;
    const int t0 = blockIdx.x * K1_OUT;
    const int tsb = t0 - 64;                 // first staged t (64-t halo)

    // ---- stage x coalesced (float4 over channels) -> channel-major swizzled LDS
    {
        const int cq = (tid & 7) * 4;
        const int tr = tid >> 3;             // 0..63
        const float* xb = x + (size_t)b * L * D + c0 + cq;
#pragma unroll
        for (int it = 0; it < 4; ++it) {
            const int p = it * 64 + tr;
            const int t = tsb + p;
            float4 v = make_float4(0.f, 0.f, 0.f, 0.f);
            if (t >= 0 && t < L) v = *reinterpret_cast<const float4*>(xb + (size_t)t * D);
            const int ph = phie(p);
            lds[(cq + 0) * K1_S + ph] = __float_as_uint(v.x);
            lds[(cq + 1) * K1_S + ph] = __float_as_uint(v.y);
            lds[(cq + 2) * K1_S + ph] = __float_as_uint(v.z);
            lds[(cq + 3) * K1_S + ph] = __float_as_uint(v.w);
        }
    }
    __syncthreads();

    // ---- compute: 4 channel-chains per wave, 2 sequential groups of 2
    {
        const int lane = tid & 63;
        const int wv   = tid >> 6;           // 0..7
        const int p0  = 4 * lane;
        const int ph0 = phie(p0);            // even; p0..p0+3 stay contiguous

#pragma unroll
        for (int g = 0; g < 2; ++g) {
            // wave-uniform channels -> scalar (SGPR) coefficient loads
            int cu[2];
            float h00[2], h01[2], h10[2], h11[2];
#pragma unroll
            for (int u = 0; u < 2; ++u) {
                cu[u] = __builtin_amdgcn_readfirstlane(c0 + wv + 8 * (2 * g + u));
                h00[u] = h0[2 * cu[u]];  h01[u] = h0[2 * cu[u] + 1];
                h10[u] = h1[2 * cu[u]];  h11[u] = h1[2 * cu[u] + 1];
            }

            float A[2][4], Y[2][4];
#pragma unroll
            for (int u = 0; u < 2; ++u) {
                const int base = (wv + 8 * (2 * g + u)) * K1_S + ph0;
                const uint2 r0 = *reinterpret_cast<const uint2*>(&lds[base]);
                const uint2 r1 = *reinterpret_cast<const uint2*>(&lds[base + 2]);
                A[u][0] = __uint_as_float(r0.x); A[u][1] = __uint_as_float(r0.y);
                A[u][2] = __uint_as_float(r1.x); A[u][3] = __uint_as_float(r1.y);
                const float w0 = w[cu[u]];
#pragma unroll
                for (int i = 0; i < 4; ++i) Y[u][i] = w0 * A[u][i];
            }

            // d=1: look = {lane-1 a3, a0, a1, a2}
#pragma unroll
            for (int u = 0; u < 2; ++u)
                lvl4(A[u], Y[u], sh1(A[u][3]), A[u][0], A[u][1], A[u][2],
                     h00[u], h01[u], h10[u], h11[u], w[1 * D + cu[u]]);
            // d=2
#pragma unroll
            for (int u = 0; u < 2; ++u)
                lvl4(A[u], Y[u], sh1(A[u][2]), sh1(A[u][3]), A[u][0], A[u][1],
                     h00[u], h01[u], h10[u], h11[u], w[2 * D + cu[u]]);
            // d=4: full slab of lane-1
#pragma unroll
            for (int u = 0; u < 2; ++u)
                lvl4(A[u], Y[u], sh1(A[u][0]), sh1(A[u][1]), sh1(A[u][2]), sh1(A[u][3]),
                     h00[u], h01[u], h10[u], h11[u], w[3 * D + cu[u]]);
            // d=8,16,32: lane-m slabs, m=2,4,8 (clamp garbage lands in halo p<64)
#pragma unroll
            for (int u = 0; u < 2; ++u)
                lvl4(A[u], Y[u], __shfl_up(A[u][0], 2), __shfl_up(A[u][1], 2),
                     __shfl_up(A[u][2], 2), __shfl_up(A[u][3], 2),
                     h00[u], h01[u], h10[u], h11[u], w[4 * D + cu[u]]);
#pragma unroll
            for (int u = 0; u < 2; ++u)
                lvl4(A[u], Y[u], __shfl_up(A[u][0], 4), __shfl_up(A[u][1], 4),
                     __shfl_up(A[u][2], 4), __shfl_up(A[u][3], 4),
                     h00[u], h01[u], h10[u], h11[u], w[5 * D + cu[u]]);
#pragma unroll
            for (int u = 0; u < 2; ++u)
                lvl4(A[u], Y[u], __shfl_up(A[u][0], 8), __shfl_up(A[u][1], 8),
                     __shfl_up(A[u][2], 8), __shfl_up(A[u][3], 8),
                     h00[u], h01[u], h10[u], h11[u], w[6 * D + cu[u]]);

            // write back packed (b64 pairs); rows are wave-private -> no barrier
#pragma unroll
            for (int u = 0; u < 2; ++u) {
                const int base = (wv + 8 * (2 * g + u)) * K1_S + ph0;
                uint2 w0v, w1v;
                w0v.x = pk2(Y[u][0], A[u][0]); w0v.y = pk2(Y[u][1], A[u][1]);
                w1v.x = pk2(Y[u][2], A[u][2]); w1v.y = pk2(Y[u][3], A[u][3]);
                *reinterpret_cast<uint2*>(&lds[base])     = w0v;
                *reinterpret_cast<uint2*>(&lds[base + 2]) = w1v;
            }
        }
    }
    __syncthreads();

    // ---- coalesced packed store, valid p in [64, 256)
    {
        const int cq = (tid & 7) * 4;
        const int tr = tid >> 3;             // 0..63
        uint32_t* ob = out_pk + (size_t)b * L * D + c0 + cq;
#pragma unroll
        for (int it = 0; it < 3; ++it) {
            const int p = 64 + it * 64 + tr;
            const int t = tsb + p;
            if (t < L) {
                const int ph = phie(p);
                uint4 v;
                v.x = lds[(cq + 0) * K1_S + ph];
                v.y = lds[(cq + 1) * K1_S + ph];
                v.z = lds[(cq + 2) * K1_S + ph];
                v.w = lds[(cq + 3) * K1_S + ph];
                *reinterpret_cast<uint4*>(ob + (size_t)t * D) = v;
            }
        }
    }
}

// ---------------- Kernel 2: levels 6..12 + final terms ----------------
// t = t1*64 + t2; coupling only along t1 (128 long). In-place on d_out.
__global__ __launch_bounds__(512, 8)
void mrl_k2(const float* __restrict__ h0, const float* __restrict__ h1,
            const float* __restrict__ w, float* __restrict__ y) {
    __shared__ uint32_t lds[K2_CT * K2_T2 * K2_S];   // 34.3 KB
    const int tid = threadIdx.x;
    const int b   = blockIdx.z;
    const int c0  = blockIdx.y * K2_CT;
    const int t2a = blockIdx.x * K2_T2;
    uint32_t* yb = reinterpret_cast<uint32_t*>(y) + (size_t)b * L * D + c0;

    // ---- stage packed {y1,a6} coalesced (uint4 over channels)
    {
        const int cq  = (tid & 7) * 4;
        const int t2i = (tid >> 3) & 1;
        const int t1r = tid >> 4;            // 0..31
#pragma unroll
        for (int it = 0; it < 4; ++it) {
            const int t1 = it * 32 + t1r;
            const int t  = t1 * 64 + t2a + t2i;
            const uint4 v = *reinterpret_cast<const uint4*>(yb + (size_t)t * D + cq);
            const int ph = phie(t1);
            lds[((cq + 0) * 2 + t2i) * K2_S + ph] = v.x;
            lds[((cq + 1) * 2 + t2i) * K2_S + ph] = v.y;
            lds[((cq + 2) * 2 + t2i) * K2_S + ph] = v.z;
            lds[((cq + 3) * 2 + t2i) * K2_S + ph] = v.w;
        }
    }
    __syncthreads();

    // ---- compute: 8 row-chains per wave, 2 sequential groups of 4
    {
        const int lane = tid & 63;
        const int wv   = tid >> 6;           // 0..7
        const int ph0  = phie(2 * lane);     // even; pair (2l, 2l+1) contiguous

#pragma unroll
        for (int g = 0; g < 2; ++g) {
            int cu[4];
            float h00[4], h01[4], h10[4], h11[4];
#pragma unroll
            for (int q = 0; q < 4; ++q) {
                const int qq = 4 * g + q;
                cu[q] = __builtin_amdgcn_readfirstlane(c0 + ((wv + 8 * qq) >> 1));
                h00[q] = h0[2 * cu[q]];  h01[q] = h0[2 * cu[q] + 1];
                h10[q] = h1[2 * cu[q]];  h11[q] = h1[2 * cu[q] + 1];
            }

            float A0[4], A1[4], Y0[4], Y1[4];
#pragma unroll
            for (int q = 0; q < 4; ++q) {
                const int base = (wv + 8 * (4 * g + q)) * K2_S + ph0;
                const uint2 r = *reinterpret_cast<const uint2*>(&lds[base]);
                A0[q] = up_hi(r.x); Y0[q] = up_lo(r.x);
                A1[q] = up_hi(r.y); Y1[q] = up_lo(r.y);
            }

            // t1-dilation 1 (level 6): l0 = lane-1's a1 (0 at t1<0), l1 = own a0
#pragma unroll
            for (int q = 0; q < 4; ++q) {
                const float wj = w[7 * D + cu[q]];
                const float l0 = sh1z(A1[q], lane);
                const float l1 = A0[q];
                const float bv0 = l0 * h10[q] + A0[q] * h11[q];
                const float bv1 = l1 * h10[q] + A1[q] * h11[q];
                Y0[q] = fmaf(wj, bv0, Y0[q]);
                Y1[q] = fmaf(wj, bv1, Y1[q]);
                A0[q] = l0 * h00[q] + A0[q] * h01[q];
                A1[q] = l1 * h00[q] + A1[q] * h01[q];
            }
            // t1-dilation 2: lane-1 full slab (zero at lane 0 = t1<0)
#pragma unroll
            for (int q = 0; q < 4; ++q) {
                const float wj = w[8 * D + cu[q]];
                const float l0 = sh1z(A0[q], lane);
                const float l1 = sh1z(A1[q], lane);
                const float bv0 = l0 * h10[q] + A0[q] * h11[q];
                const float bv1 = l1 * h10[q] + A1[q] * h11[q];
                Y0[q] = fmaf(wj, bv0, Y0[q]);
                Y1[q] = fmaf(wj, bv1, Y1[q]);
                A0[q] = l0 * h00[q] + A0[q] * h01[q];
                A1[q] = l1 * h00[q] + A1[q] * h01[q];
            }
            // t1-dilation 4,8,16,32,64: lane-m slabs, m=2,4,8,16,32 (masked shfl)
#pragma unroll
            for (int k = 0; k < 5; ++k) {
                const int m = 2 << k;
#pragma unroll
                for (int q = 0; q < 4; ++q) {
                    const float wj = w[(9 + k) * D + cu[q]];
                    const float s0 = __shfl_up(A0[q], m);
                    const float s1 = __shfl_up(A1[q], m);
                    const bool ok = (lane >= m);
                    const float l0 = ok ? s0 : 0.f;
                    const float l1 = ok ? s1 : 0.f;
                    const float bv0 = l0 * h10[q] + A0[q] * h11[q];
                    const float bv1 = l1 * h10[q] + A1[q] * h11[q];
                    Y0[q] = fmaf(wj, bv0, Y0[q]);
                    Y1[q] = fmaf(wj, bv1, Y1[q]);
                    A0[q] = l0 * h00[q] + A0[q] * h01[q];
                    A1[q] = l1 * h00[q] + A1[q] * h01[q];
                }
            }
            // final a-term + write back (wave-private rows -> no barrier)
#pragma unroll
            for (int q = 0; q < 4; ++q) {
                const float w14 = w[14 * D + cu[q]];
                const int base = (wv + 8 * (4 * g + q)) * K2_S + ph0;
                uint2 wv2;
                wv2.x = __float_as_uint(fmaf(w14, A0[q], Y0[q]));
                wv2.y = __float_as_uint(fmaf(w14, A1[q], Y1[q]));
                *reinterpret_cast<uint2*>(&lds[base]) = wv2;
            }
        }
    }
    __syncthreads();

    // ---- coalesced final f32 store
    {
        const int cq = (tid & 7) * 4;
        const int rq = tid >> 3;             // 0..63
#pragma unroll
        for (int it = 0; it < 4; ++it) {
            const int row = it * 64 + rq;    // 0..255
            const int t1 = row >> 1, t2i = row & 1;
            const int t  = t1 * 64 + t2a + t2i;
            const int ph = phie(t1);
            uint4 v;
            v.x = lds[((cq + 0) * 2 + t2i) * K2_S + ph];
            v.y = lds[((cq + 1) * 2 + t2i) * K2_S + ph];
            v.z = lds[((cq + 2) * 2 + t2i) * K2_S + ph];
            v.w = lds[((cq + 3) * 2 + t2i) * K2_S + ph];
            *reinterpret_cast<uint4*>(yb + (size_t)t * D + cq) = v;
        }
    }
}

} // namespace

extern "C" void kernel_launch(void* const* d_in, const int* in_sizes, int n_in,
                              void* d_out, int out_size, void* d_ws, size_t ws_size,
                              hipStream_t stream) {
    const float* x  = (const float*)d_in[0];
    const float* h0 = (const float*)d_in[1];
    const float* h1 = (const float*)d_in[2];
    const float* w  = (const float*)d_in[3];
    float* y = (float*)d_out;
    (void)d_ws; (void)ws_size;

    const int B = in_sizes[0] / (L * D);   // = 8

    dim3 g1((L + K1_OUT - 1) / K1_OUT, D / K1_CT, B);  // (43, 8, 8)
    dim3 g2(64 / K2_T2, D / K2_CT, B);                 // (32, 8, 8)

    mrl_k1<<<g1, 512, 0, stream>>>(x, h0, h1, w, (uint32_t*)y);
    mrl_k2<<<g2, 512, 0, stream>>>(h0, h1, w, y);
}

// Round 10
// 152.577 us; speedup vs baseline: 1.1241x; 1.0564x over previous
//
#include <hip/hip_runtime.h>
#include <hip/hip_fp16.h>
#include <stdint.h>

namespace {

constexpr int L = 8192;
constexpr int D = 256;

// K1: levels 0..5 (dilation 1..32). Block 512 thr = 8 waves, 32-channel tile,
// 256 staged t (64 halo + 192 valid). Lane owns 4 t; wave owns 4 channels
// processed as 2 sequential CHANNEL-PAIRS packed in __half2 lanes.
constexpr int K1_CT  = 32;
constexpr int K1_OUT = 192;
constexpr int K1_S   = 270;   // words/row; even (b64 align), mod 32 = 14

// K2: levels 6..12 (t1-dilation 1..64). Block 512 thr, 32-ch x 2-t2 tile.
// Lane owns t1 {2l,2l+1}; wave owns 8 (c,t2) rows as 4 channel-pairs.
constexpr int K2_CT = 32;
constexpr int K2_T2 = 2;
constexpr int K2_S  = 134;    // words/row; even, mod 32 = 6

// quad-preserving swizzle: consecutive p stay consecutive within 32-block,
// even p stays even (b64 alignment), +2 jump per 32 breaks bank alignment.
__device__ __forceinline__ int phie(int p) { return p + 2 * (p >> 5); }

__device__ __forceinline__ uint32_t h2u(__half2 v) { return __builtin_bit_cast(uint32_t, v); }
__device__ __forceinline__ __half2 u2h(uint32_t v) { return __builtin_bit_cast(__half2, v); }

// packed shuffle-up (ds_bpermute moves 2 channels at once)
__device__ __forceinline__ __half2 h2up(__half2 v, int m) {
    return u2h((uint32_t)__shfl_up((int)h2u(v), m));
}
// zero-filled variant (t < 0 reads exact 0)
__device__ __forceinline__ __half2 h2upz(__half2 v, int m, int lane) {
    const int s = __shfl_up((int)h2u(v), m);
    return u2h((lane >= m) ? (uint32_t)s : 0u);
}

// one dilation level over 4 packed t-elements (looks captured pre-update)
__device__ __forceinline__ void plvl4(__half2 (&A)[4], __half2 (&Y)[4],
                                      const __half2 (&lk)[4],
                                      __half2 c00, __half2 c01, __half2 c10,
                                      __half2 c11, __half2 wj) {
#pragma unroll
    for (int i = 0; i < 4; ++i) {
        const __half2 bv = __hfma2(A[i], c11, __hmul2(lk[i], c10));
        Y[i] = __hfma2(wj, bv, Y[i]);
        A[i] = __hfma2(A[i], c01, __hmul2(lk[i], c00));
    }
}

__device__ __forceinline__ void plvl2(__half2& A0, __half2& A1, __half2& Y0, __half2& Y1,
                                      __half2 l0, __half2 l1,
                                      __half2 c00, __half2 c01, __half2 c10,
                                      __half2 c11, __half2 wj) {
    const __half2 bv0 = __hfma2(A0, c11, __hmul2(l0, c10));
    const __half2 bv1 = __hfma2(A1, c11, __hmul2(l1, c10));
    Y0 = __hfma2(wj, bv0, Y0);
    Y1 = __hfma2(wj, bv1, Y1);
    A0 = __hfma2(A0, c01, __hmul2(l0, c00));
    A1 = __hfma2(A1, c01, __hmul2(l1, c00));
}

// ---------------- Kernel 1: levels 0..5 ----------------
__global__ __launch_bounds__(512, 8)
void mrl_k1(const float* __restrict__ x, const float* __restrict__ h0,
            const float* __restrict__ h1, const float* __restrict__ w,
            uint32_t* __restrict__ out_pk) {
    __shared__ uint32_t lds[K1_CT * K1_S];   // 34.6 KB; f32 x, then packed out
    const int tid = threadIdx.x;
    const int b  = blockIdx.z;
    const int c0 = blockIdx.y * K1_CT;
    const int t0 = blockIdx.x * K1_OUT;
    const int tsb = t0 - 64;                 // first staged t (64-t halo)

    // ---- stage x: tasks (t-pair pr, quad cq); b64 LDS writes per channel
    {
        const float* xb = x + (size_t)b * L * D + c0;
#pragma unroll
        for (int it = 0; it < 2; ++it) {
            const int tau = tid + 512 * it;
            const int cq = (tau & 7) * 4;
            const int pr = tau >> 3;         // 0..127, t-pair (tsb+2pr, +1)
            const int t = tsb + 2 * pr;
            float4 v0 = make_float4(0.f, 0.f, 0.f, 0.f);
            float4 v1 = v0;
            if (t >= 0 && t < L)
                v0 = *reinterpret_cast<const float4*>(xb + (size_t)t * D + cq);
            if (t + 1 >= 0 && t + 1 < L)
                v1 = *reinterpret_cast<const float4*>(xb + (size_t)(t + 1) * D + cq);
            const int ph = phie(2 * pr);     // even; +1 = phie(2pr+1)
            uint2 p0 = make_uint2(__float_as_uint(v0.x), __float_as_uint(v1.x));
            uint2 p1 = make_uint2(__float_as_uint(v0.y), __float_as_uint(v1.y));
            uint2 p2 = make_uint2(__float_as_uint(v0.z), __float_as_uint(v1.z));
            uint2 p3 = make_uint2(__float_as_uint(v0.w), __float_as_uint(v1.w));
            *reinterpret_cast<uint2*>(&lds[(cq + 0) * K1_S + ph]) = p0;
            *reinterpret_cast<uint2*>(&lds[(cq + 1) * K1_S + ph]) = p1;
            *reinterpret_cast<uint2*>(&lds[(cq + 2) * K1_S + ph]) = p2;
            *reinterpret_cast<uint2*>(&lds[(cq + 3) * K1_S + ph]) = p3;
        }
    }
    __syncthreads();

    // ---- compute: 2 channel-pairs per wave, packed fp16
    {
        const int lane = tid & 63;
        const int wv   = tid >> 6;           // 0..7
        const int p0i  = 4 * lane;
        const int ph0  = phie(p0i);          // even; p0..p0+3 contiguous

#pragma unroll
        for (int u = 0; u < 2; ++u) {
            const int rA = wv + 16 * u;      // wave-private channel rows
            const int rB = rA + 8;
            const int cA = __builtin_amdgcn_readfirstlane(c0 + rA);
            const int cB = __builtin_amdgcn_readfirstlane(c0 + rB);
            // coefficients packed {chanA lo, chanB hi}
            const __half2 c00 = __floats2half2_rn(h0[2*cA],   h0[2*cB]);
            const __half2 c01 = __floats2half2_rn(h0[2*cA+1], h0[2*cB+1]);
            const __half2 c10 = __floats2half2_rn(h1[2*cA],   h1[2*cB]);
            const __half2 c11 = __floats2half2_rn(h1[2*cA+1], h1[2*cB+1]);
            const __half2 w0v = __floats2half2_rn(w[cA], w[cB]);
            __half2 wj[6];
#pragma unroll
            for (int j = 0; j < 6; ++j)
                wj[j] = __floats2half2_rn(w[(j+1)*D + cA], w[(j+1)*D + cB]);

            // read both rows (f32, 2 b64 each) and pack channel-pairs
            const uint32_t* pa = &lds[rA * K1_S + ph0];
            const uint32_t* pb = &lds[rB * K1_S + ph0];
            const uint2 ra0 = *reinterpret_cast<const uint2*>(pa);
            const uint2 ra1 = *reinterpret_cast<const uint2*>(pa + 2);
            const uint2 rb0 = *reinterpret_cast<const uint2*>(pb);
            const uint2 rb1 = *reinterpret_cast<const uint2*>(pb + 2);
            __half2 A[4], Y[4], lk[4];
            A[0] = __floats2half2_rn(__uint_as_float(ra0.x), __uint_as_float(rb0.x));
            A[1] = __floats2half2_rn(__uint_as_float(ra0.y), __uint_as_float(rb0.y));
            A[2] = __floats2half2_rn(__uint_as_float(ra1.x), __uint_as_float(rb1.x));
            A[3] = __floats2half2_rn(__uint_as_float(ra1.y), __uint_as_float(rb1.y));
#pragma unroll
            for (int i = 0; i < 4; ++i) Y[i] = __hmul2(w0v, A[i]);

            // d=1: look = {lane-1 a3, a0, a1, a2}
            lk[0] = h2up(A[3], 1); lk[1] = A[0]; lk[2] = A[1]; lk[3] = A[2];
            plvl4(A, Y, lk, c00, c01, c10, c11, wj[0]);
            // d=2
            lk[0] = h2up(A[2], 1); lk[1] = h2up(A[3], 1); lk[2] = A[0]; lk[3] = A[1];
            plvl4(A, Y, lk, c00, c01, c10, c11, wj[1]);
            // d=4: full slab of lane-1
            lk[0] = h2up(A[0], 1); lk[1] = h2up(A[1], 1);
            lk[2] = h2up(A[2], 1); lk[3] = h2up(A[3], 1);
            plvl4(A, Y, lk, c00, c01, c10, c11, wj[2]);
            // d=8,16,32: lane-m slabs, m=2,4,8 (clamp garbage stays in halo p<64)
            lk[0] = h2up(A[0], 2); lk[1] = h2up(A[1], 2);
            lk[2] = h2up(A[2], 2); lk[3] = h2up(A[3], 2);
            plvl4(A, Y, lk, c00, c01, c10, c11, wj[3]);
            lk[0] = h2up(A[0], 4); lk[1] = h2up(A[1], 4);
            lk[2] = h2up(A[2], 4); lk[3] = h2up(A[3], 4);
            plvl4(A, Y, lk, c00, c01, c10, c11, wj[4]);
            lk[0] = h2up(A[0], 8); lk[1] = h2up(A[1], 8);
            lk[2] = h2up(A[2], 8); lk[3] = h2up(A[3], 8);
            plvl4(A, Y, lk, c00, c01, c10, c11, wj[5]);

            // write back packed u32 {y fp16 lo, a fp16 hi} per (t, channel)
            uint32_t wA[4], wB[4];
#pragma unroll
            for (int i = 0; i < 4; ++i) {
                const uint32_t Au = h2u(A[i]), Yu = h2u(Y[i]);
                wA[i] = (Yu & 0xffffu) | (Au << 16);
                wB[i] = (Yu >> 16)     | (Au & 0xffff0000u);
            }
            uint32_t* qa = &lds[rA * K1_S + ph0];
            uint32_t* qb = &lds[rB * K1_S + ph0];
            *reinterpret_cast<uint2*>(qa)     = make_uint2(wA[0], wA[1]);
            *reinterpret_cast<uint2*>(qa + 2) = make_uint2(wA[2], wA[3]);
            *reinterpret_cast<uint2*>(qb)     = make_uint2(wB[0], wB[1]);
            *reinterpret_cast<uint2*>(qb + 2) = make_uint2(wB[2], wB[3]);
        }
    }
    __syncthreads();

    // ---- coalesced packed store, valid p in [64, 256)
    {
        const int cq = (tid & 7) * 4;
        const int tr = tid >> 3;             // 0..63
        uint32_t* ob = out_pk + (size_t)b * L * D + c0 + cq;
#pragma unroll
        for (int it = 0; it < 3; ++it) {
            const int p = 64 + it * 64 + tr;
            const int t = tsb + p;
            if (t < L) {
                const int ph = phie(p);
                uint4 v;
                v.x = lds[(cq + 0) * K1_S + ph];
                v.y = lds[(cq + 1) * K1_S + ph];
                v.z = lds[(cq + 2) * K1_S + ph];
                v.w = lds[(cq + 3) * K1_S + ph];
                *reinterpret_cast<uint4*>(ob + (size_t)t * D) = v;
            }
        }
    }
}

// ---------------- Kernel 2: levels 6..12 + final terms ----------------
// t = t1*64 + t2; coupling only along t1 (128 long). In-place on d_out.
__global__ __launch_bounds__(512, 8)
void mrl_k2(const float* __restrict__ h0, const float* __restrict__ h1,
            const float* __restrict__ w, float* __restrict__ y) {
    __shared__ uint32_t lds[K2_CT * K2_T2 * K2_S];   // 34.3 KB
    const int tid = threadIdx.x;
    const int b   = blockIdx.z;
    const int c0  = blockIdx.y * K2_CT;
    const int t2a = blockIdx.x * K2_T2;
    uint32_t* yb = reinterpret_cast<uint32_t*>(y) + (size_t)b * L * D + c0;

    // ---- stage packed {y1,a6}: tasks (t1-pair u, t2i, quad cq); b64 writes
    {
#pragma unroll
        for (int it = 0; it < 2; ++it) {
            const int tau = tid + 512 * it;
            const int cq  = (tau & 7) * 4;
            const int t2i = (tau >> 3) & 1;
            const int u   = tau >> 4;        // 0..63, t1 pair (2u, 2u+1)
            const uint4 v0 = *reinterpret_cast<const uint4*>(
                yb + (size_t)((2*u)   * 64 + t2a + t2i) * D + cq);
            const uint4 v1 = *reinterpret_cast<const uint4*>(
                yb + (size_t)((2*u+1) * 64 + t2a + t2i) * D + cq);
            const int ph = phie(2 * u);
            *reinterpret_cast<uint2*>(&lds[((cq + 0) * 2 + t2i) * K2_S + ph]) = make_uint2(v0.x, v1.x);
            *reinterpret_cast<uint2*>(&lds[((cq + 1) * 2 + t2i) * K2_S + ph]) = make_uint2(v0.y, v1.y);
            *reinterpret_cast<uint2*>(&lds[((cq + 2) * 2 + t2i) * K2_S + ph]) = make_uint2(v0.z, v1.z);
            *reinterpret_cast<uint2*>(&lds[((cq + 3) * 2 + t2i) * K2_S + ph]) = make_uint2(v0.w, v1.w);
        }
    }
    __syncthreads();

    // ---- compute: 4 channel-pairs per wave (rows r and r+32 share t2i)
    {
        const int lane = tid & 63;
        const int wv   = tid >> 6;           // 0..7
        const int ph0  = phie(2 * lane);     // even; pair (2l, 2l+1) contiguous

#pragma unroll
        for (int q = 0; q < 4; ++q) {
            const int rowA = wv + 8 * q;     // rowB = rowA + 32, same t2 parity
            const int cA = __builtin_amdgcn_readfirstlane(c0 + (rowA >> 1));
            const int cB = cA + 16;
            const __half2 c00 = __floats2half2_rn(h0[2*cA],   h0[2*cB]);
            const __half2 c01 = __floats2half2_rn(h0[2*cA+1], h0[2*cB+1]);
            const __half2 c10 = __floats2half2_rn(h1[2*cA],   h1[2*cB]);
            const __half2 c11 = __floats2half2_rn(h1[2*cA+1], h1[2*cB+1]);
            __half2 wj[7];
#pragma unroll
            for (int j = 0; j < 7; ++j)
                wj[j] = __floats2half2_rn(w[(7+j)*D + cA], w[(7+j)*D + cB]);
            const __half2 w14v = __floats2half2_rn(w[14*D + cA], w[14*D + cB]);

            uint32_t* pa = &lds[rowA * K2_S + ph0];
            uint32_t* pb = &lds[(rowA + 32) * K2_S + ph0];
            const uint2 wa = *reinterpret_cast<const uint2*>(pa);
            const uint2 wb = *reinterpret_cast<const uint2*>(pb);
            // unpack {y lo16, a hi16} into channel-packed half2
            __half2 A0 = u2h((wa.x >> 16) | (wb.x & 0xffff0000u));
            __half2 Y0 = u2h((wa.x & 0xffffu) | (wb.x << 16));
            __half2 A1 = u2h((wa.y >> 16) | (wb.y & 0xffff0000u));
            __half2 Y1 = u2h((wa.y & 0xffffu) | (wb.y << 16));

            // t1-dilation 1 (level 6): l0 = lane-1's a1 (0 at t1<0), l1 = own a0
            {
                const __half2 l0 = h2upz(A1, 1, lane);
                const __half2 l1 = A0;
                plvl2(A0, A1, Y0, Y1, l0, l1, c00, c01, c10, c11, wj[0]);
            }
            // t1-dilation 2,4,8,16,32,64 -> lane-m slabs, m=1..32 (zero-masked)
#pragma unroll
            for (int k = 0; k < 6; ++k) {
                const int m = 1 << k;
                const __half2 l0 = h2upz(A0, m, lane);
                const __half2 l1 = h2upz(A1, m, lane);
                plvl2(A0, A1, Y0, Y1, l0, l1, c00, c01, c10, c11, wj[1 + k]);
            }
            // final a-term
            Y0 = __hfma2(w14v, A0, Y0);
            Y1 = __hfma2(w14v, A1, Y1);

            // write back final f32 y per row (b64 each)
            uint2 oa, ob;
            oa.x = __float_as_uint(__low2float(Y0));
            oa.y = __float_as_uint(__low2float(Y1));
            ob.x = __float_as_uint(__high2float(Y0));
            ob.y = __float_as_uint(__high2float(Y1));
            *reinterpret_cast<uint2*>(pa) = oa;
            *reinterpret_cast<uint2*>(pb) = ob;
        }
    }
    __syncthreads();

    // ---- coalesced final f32 store
    {
        const int cq = (tid & 7) * 4;
        const int rq = tid >> 3;             // 0..63
#pragma unroll
        for (int it = 0; it < 4; ++it) {
            const int row = it * 64 + rq;    // 0..255
            const int t1 = row >> 1, t2i = row & 1;
            const int t  = t1 * 64 + t2a + t2i;
            const int ph = phie(t1);
            uint4 v;
            v.x = lds[((cq + 0) * 2 + t2i) * K2_S + ph];
            v.y = lds[((cq + 1) * 2 + t2i) * K2_S + ph];
            v.z = lds[((cq + 2) * 2 + t2i) * K2_S + ph];
            v.w = lds[((cq + 3) * 2 + t2i) * K2_S + ph];
            *reinterpret_cast<uint4*>(yb + (size_t)t * D + cq) = v;
        }
    }
}

} // namespace

extern "C" void kernel_launch(void* const* d_in, const int* in_sizes, int n_in,
                              void* d_out, int out_size, void* d_ws, size_t ws_size,
                              hipStream_t stream) {
    const float* x  = (const float*)d_in[0];
    const float* h0 = (const float*)d_in[1];
    const float* h1 = (const float*)d_in[2];
    const float* w  = (const float*)d_in[3];
    float* y = (float*)d_out;
    (void)d_ws; (void)ws_size;

    const int B = in_sizes[0] / (L * D);   // = 8

    dim3 g1((L + K1_OUT - 1) / K1_OUT, D / K1_CT, B);  // (43, 8, 8)
    dim3 g2(64 / K2_T2, D / K2_CT, B);                 // (32, 8, 8)

    mrl_k1<<<g1, 512, 0, stream>>>(x, h0, h1, w, (uint32_t*)y);
    mrl_k2<<<g2, 512, 0, stream>>>(h0, h1, w, y);
}

// Round 11
// 152.435 us; speedup vs baseline: 1.1251x; 1.0009x over previous
//
#include <hip/hip_runtime.h>
#include <hip/hip_fp16.h>
#include <stdint.h>

namespace {

constexpr int L = 8192;
constexpr int D = 256;
constexpr int CT = 32;       // channels per tile (both kernels)
constexpr int K1_OUT = 192;  // valid t per k1 block (64-t halo)
constexpr int SW = 134;      // LDS row stride in words (128 data + swizzle pad)

// word-index swizzle (0..127 -> 0..133), even-preserving for b64 pairs
__device__ __forceinline__ int phw(int pw) { return pw + 2 * (pw >> 5); }

__device__ __forceinline__ uint32_t h2u(__half2 v) { return __builtin_bit_cast(uint32_t, v); }
__device__ __forceinline__ __half2 u2h(uint32_t v) { return __builtin_bit_cast(__half2, v); }
__device__ __forceinline__ uint32_t pkf(float a, float b) { return h2u(__floats2half2_rn(a, b)); }

__device__ __forceinline__ uint32_t shfl_u32(uint32_t v, int m) {
    return (uint32_t)__shfl_up((int)v, m);
}

// one level update on a packed pair: b = lk*h1 + a*h1'; y += wj*b; a = lk*h0 + a*h0'
__device__ __forceinline__ void upd(__half2& A, __half2& Y, __half2 lk,
                                    __half2 c00, __half2 c01, __half2 c10,
                                    __half2 c11, __half2 wj) {
    const __half2 bv = __hfma2(A, c11, __hmul2(lk, c10));
    Y = __hfma2(wj, bv, Y);
    A = __hfma2(A, c01, __hmul2(lk, c00));
}

// ---------------- Kernel 1: levels 0..5 (d = 1..32) ----------------
// 8 waves; lane = (ch 0..3)*16 + chunk; lane owns 16 consecutive t of one
// channel, time-packed fp16 (8 u32). Wave = 4 channels x 256 t, single pass.
// Shfl garbage (clamp / channel-cross) confined to t<32 (halo); propagation
// bound: garbage at level d reaches < d + sum(later dilations) <= 63 < 64.
__global__ __launch_bounds__(512, 8)
void mrl_k1(const float* __restrict__ x, const float* __restrict__ h0,
            const float* __restrict__ h1, const float* __restrict__ w,
            uint32_t* __restrict__ gout) {
    __shared__ uint32_t lds[2 * CT * SW];   // rows 0..31: x->y words; 32..63: a words (34.3 KB)
    const int tid = threadIdx.x;
    const int b  = blockIdx.z;
    const int c0 = blockIdx.y * CT;
    const int t0 = blockIdx.x * K1_OUT;
    const int tsb = t0 - 64;                // first staged t (64-t halo)

    // ---- stage x: fp16 time-pair words per channel row
    {
        const float* xb = x + (size_t)b * L * D + c0;
#pragma unroll
        for (int it = 0; it < 2; ++it) {
            const int tau = tid + 512 * it;
            const int cq = (tau & 7) * 4;
            const int pw = tau >> 3;         // 0..127: word = {t, t+1}, t = tsb+2pw
            const int t = tsb + 2 * pw;
            float4 v0 = make_float4(0.f, 0.f, 0.f, 0.f), v1 = v0;
            if (t >= 0 && t < L)
                v0 = *reinterpret_cast<const float4*>(xb + (size_t)t * D + cq);
            if (t + 1 >= 0 && t + 1 < L)
                v1 = *reinterpret_cast<const float4*>(xb + (size_t)(t + 1) * D + cq);
            const int ph = phw(pw);
            lds[(cq + 0) * SW + ph] = pkf(v0.x, v1.x);
            lds[(cq + 1) * SW + ph] = pkf(v0.y, v1.y);
            lds[(cq + 2) * SW + ph] = pkf(v0.z, v1.z);
            lds[(cq + 3) * SW + ph] = pkf(v0.w, v1.w);
        }
    }
    __syncthreads();

    // ---- compute: single pass, 24 shfl/wave
    {
        const int lane  = tid & 63;
        const int wv    = tid >> 6;          // 0..7
        const int ch    = lane >> 4;         // 0..3
        const int chunk = lane & 15;         // owns t in [16*chunk, 16*chunk+16)
        const int row   = wv * 4 + ch;       // wave-private channel rows
        const int c     = c0 + row;

        const __half2 c00 = __half2half2(__float2half(h0[2 * c]));
        const __half2 c01 = __half2half2(__float2half(h0[2 * c + 1]));
        const __half2 c10 = __half2half2(__float2half(h1[2 * c]));
        const __half2 c11 = __half2half2(__float2half(h1[2 * c + 1]));
        const __half2 w0v = __half2half2(__float2half(w[c]));
        __half2 wj[6];
#pragma unroll
        for (int j = 0; j < 6; ++j)
            wj[j] = __half2half2(__float2half(w[(j + 1) * D + c]));

        uint32_t* Sr = &lds[row * SW];
        uint32_t* Ar = &lds[(CT + row) * SW];
        const int pb = 8 * chunk;            // first word index owned by lane

        __half2 R[8], Yw[8];
#pragma unroll
        for (int k = 0; k < 4; ++k) {
            const uint2 r = *reinterpret_cast<const uint2*>(&Sr[phw(pb + 2 * k)]);
            R[2 * k]     = u2h(r.x);
            R[2 * k + 1] = u2h(r.y);
        }
#pragma unroll
        for (int j = 0; j < 8; ++j) Yw[j] = __hmul2(w0v, R[j]);

        __half2 lk[8];
        // d=1: 1 shfl + 16-bit funnel combine
        {
            uint32_t rm1 = shfl_u32(h2u(R[7]), 1);
#pragma unroll
            for (int j = 0; j < 8; ++j) {
                const uint32_t cur = h2u(R[j]);
                lk[j] = u2h((cur << 16) | (rm1 >> 16));
                rm1 = cur;
            }
#pragma unroll
            for (int j = 0; j < 8; ++j) upd(R[j], Yw[j], lk[j], c00, c01, c10, c11, wj[0]);
        }
        // d=2: word shift 1
        {
            lk[0] = u2h(shfl_u32(h2u(R[7]), 1));
#pragma unroll
            for (int j = 1; j < 8; ++j) lk[j] = R[j - 1];
#pragma unroll
            for (int j = 0; j < 8; ++j) upd(R[j], Yw[j], lk[j], c00, c01, c10, c11, wj[1]);
        }
        // d=4: word shift 2
        {
            lk[0] = u2h(shfl_u32(h2u(R[6]), 1));
            lk[1] = u2h(shfl_u32(h2u(R[7]), 1));
#pragma unroll
            for (int j = 2; j < 8; ++j) lk[j] = R[j - 2];
#pragma unroll
            for (int j = 0; j < 8; ++j) upd(R[j], Yw[j], lk[j], c00, c01, c10, c11, wj[2]);
        }
        // d=8: word shift 4
        {
#pragma unroll
            for (int j = 0; j < 4; ++j) lk[j] = u2h(shfl_u32(h2u(R[4 + j]), 1));
#pragma unroll
            for (int j = 4; j < 8; ++j) lk[j] = R[j - 4];
#pragma unroll
            for (int j = 0; j < 8; ++j) upd(R[j], Yw[j], lk[j], c00, c01, c10, c11, wj[3]);
        }
        // d=16: full slab of lane-1
        {
#pragma unroll
            for (int j = 0; j < 8; ++j) lk[j] = u2h(shfl_u32(h2u(R[j]), 1));
#pragma unroll
            for (int j = 0; j < 8; ++j) upd(R[j], Yw[j], lk[j], c00, c01, c10, c11, wj[4]);
        }
        // d=32: full slab of lane-2
        {
#pragma unroll
            for (int j = 0; j < 8; ++j) lk[j] = u2h(shfl_u32(h2u(R[j]), 2));
#pragma unroll
            for (int j = 0; j < 8; ++j) upd(R[j], Yw[j], lk[j], c00, c01, c10, c11, wj[5]);
        }

        // write back: y-words in place, a-words to A rows (wave-private rows)
#pragma unroll
        for (int k = 0; k < 4; ++k) {
            const int ph = phw(pb + 2 * k);
            *reinterpret_cast<uint2*>(&Sr[ph]) = make_uint2(h2u(Yw[2 * k]), h2u(Yw[2 * k + 1]));
            *reinterpret_cast<uint2*>(&Ar[ph]) = make_uint2(h2u(R[2 * k]),  h2u(R[2 * k + 1]));
        }
    }
    __syncthreads();

    // ---- store: slot (t even, c) = y-word {t,t+1}; slot (t+1, c) = a-word.
    // In-place-safe for k2 (each k2 block reads/writes its own t rows).
    {
        const int cq = (tid & 7) * 4;
        const int s  = tid >> 3;             // 0..63
        uint32_t* ob = gout + (size_t)b * L * D + c0 + cq;
#pragma unroll
        for (int it = 0; it < 2; ++it) {
            const int pw = 32 + s + 64 * it; // valid words: pw in [32,128)
            if (it == 1 && s >= 32) break;
            const int t = tsb + 2 * pw;
            if (t < L) {
                const int ph = phw(pw);
                uint4 vy, va;
                vy.x = lds[(cq + 0) * SW + ph];
                vy.y = lds[(cq + 1) * SW + ph];
                vy.z = lds[(cq + 2) * SW + ph];
                vy.w = lds[(cq + 3) * SW + ph];
                va.x = lds[(CT + cq + 0) * SW + ph];
                va.y = lds[(CT + cq + 1) * SW + ph];
                va.z = lds[(CT + cq + 2) * SW + ph];
                va.w = lds[(CT + cq + 3) * SW + ph];
                *reinterpret_cast<uint4*>(ob + (size_t)t * D)       = vy;
                *reinterpret_cast<uint4*>(ob + (size_t)(t + 1) * D) = va;
            }
        }
    }
}

// ---------------- Kernel 2: levels 6..12 + final terms ----------------
// Block = (t2-pair v, 32-channel tile, b). Words are t2-packed half2
// {t2=2v, 2v+1}; recurrence along t1 (128) is elementwise in the pair.
// Lane owns t1 {2l, 2l+1}. In-place on d_out (own t rows only).
__global__ __launch_bounds__(512, 8)
void mrl_k2(const float* __restrict__ h0, const float* __restrict__ h1,
            const float* __restrict__ w, float* __restrict__ y) {
    __shared__ uint32_t lds[2 * CT * SW];   // rows 0..31: y-words; 32..63: a-words
    const int tid = threadIdx.x;
    const int b  = blockIdx.z;
    const int c0 = blockIdx.y * CT;
    const int v  = blockIdx.x;              // t2 pair {2v, 2v+1}
    uint32_t* yb = reinterpret_cast<uint32_t*>(y) + (size_t)b * L * D;

    // ---- stage: y-word at row t, a-word at row t+1, t = t1*64 + 2v
    {
#pragma unroll
        for (int it = 0; it < 2; ++it) {
            const int tau = tid + 512 * it;
            const int cq = (tau & 7) * 4;
            const int t1 = tau >> 3;         // 0..127
            const int t  = t1 * 64 + 2 * v;
            const uint4 vy = *reinterpret_cast<const uint4*>(yb + (size_t)t * D + c0 + cq);
            const uint4 va = *reinterpret_cast<const uint4*>(yb + (size_t)(t + 1) * D + c0 + cq);
            const int ph = phw(t1);
            lds[(cq + 0) * SW + ph] = vy.x;
            lds[(cq + 1) * SW + ph] = vy.y;
            lds[(cq + 2) * SW + ph] = vy.z;
            lds[(cq + 3) * SW + ph] = vy.w;
            lds[(CT + cq + 0) * SW + ph] = va.x;
            lds[(CT + cq + 1) * SW + ph] = va.y;
            lds[(CT + cq + 2) * SW + ph] = va.z;
            lds[(CT + cq + 3) * SW + ph] = va.w;
        }
    }
    __syncthreads();

    // ---- compute: 4 channel rows per wave, sequential
    {
        const int lane = tid & 63;
        const int wv   = tid >> 6;           // 0..7
        const int ph0  = phw(2 * lane);      // even; pair (2l, 2l+1) contiguous

#pragma unroll
        for (int q = 0; q < 4; ++q) {
            const int row = wv + 8 * q;      // wave-private channel row
            const int c = __builtin_amdgcn_readfirstlane(c0 + row);
            const __half2 c00 = __half2half2(__float2half(h0[2 * c]));
            const __half2 c01 = __half2half2(__float2half(h0[2 * c + 1]));
            const __half2 c10 = __half2half2(__float2half(h1[2 * c]));
            const __half2 c11 = __half2half2(__float2half(h1[2 * c + 1]));
            __half2 wj[7];
#pragma unroll
            for (int j = 0; j < 7; ++j)
                wj[j] = __half2half2(__float2half(w[(7 + j) * D + c]));
            const __half2 w14v = __half2half2(__float2half(w[14 * D + c]));

            uint32_t* Yr = &lds[row * SW];
            uint32_t* Ar = &lds[(CT + row) * SW];
            const uint2 ry = *reinterpret_cast<const uint2*>(&Yr[ph0]);
            const uint2 ra = *reinterpret_cast<const uint2*>(&Ar[ph0]);
            __half2 Y0 = u2h(ry.x), Y1 = u2h(ry.y);
            __half2 A0 = u2h(ra.x), A1 = u2h(ra.y);

            // t1-dilation 1: l0 = lane-1's A1 (0 at t1<0), l1 = own A0
            {
                const uint32_t s = shfl_u32(h2u(A1), 1);
                const __half2 l0 = u2h(lane >= 1 ? s : 0u);
                const __half2 l1 = A0;
                upd(A0, Y0, l0, c00, c01, c10, c11, wj[0]);
                upd(A1, Y1, l1, c00, c01, c10, c11, wj[0]);
            }
            // t1-dilation 2,4,8,16,32,64 -> lane-m slabs, m=1..32 (zero-masked)
#pragma unroll
            for (int k = 0; k < 6; ++k) {
                const int m = 1 << k;
                const uint32_t s0 = shfl_u32(h2u(A0), m);
                const uint32_t s1 = shfl_u32(h2u(A1), m);
                const bool ok = (lane >= m);
                const __half2 l0 = u2h(ok ? s0 : 0u);
                const __half2 l1 = u2h(ok ? s1 : 0u);
                upd(A0, Y0, l0, c00, c01, c10, c11, wj[1 + k]);
                upd(A1, Y1, l1, c00, c01, c10, c11, wj[1 + k]);
            }
            Y0 = __hfma2(w14v, A0, Y0);
            Y1 = __hfma2(w14v, A1, Y1);
            *reinterpret_cast<uint2*>(&Yr[ph0]) = make_uint2(h2u(Y0), h2u(Y1));
        }
    }
    __syncthreads();

    // ---- store final f32: unpack y-word {t2=2v, 2v+1} -> rows t, t+1
    {
        const int cq = (tid & 7) * 4;
        float* fy = y + (size_t)b * L * D + c0 + cq;
#pragma unroll
        for (int it = 0; it < 2; ++it) {
            const int t1 = (tid >> 3) + 64 * it;  // 0..127
            const int ph = phw(t1);
            const int t  = t1 * 64 + 2 * v;
            const __half2 w0 = u2h(lds[(cq + 0) * SW + ph]);
            const __half2 w1 = u2h(lds[(cq + 1) * SW + ph]);
            const __half2 w2 = u2h(lds[(cq + 2) * SW + ph]);
            const __half2 w3 = u2h(lds[(cq + 3) * SW + ph]);
            const float4 lo = make_float4(__low2float(w0),  __low2float(w1),
                                          __low2float(w2),  __low2float(w3));
            const float4 hi = make_float4(__high2float(w0), __high2float(w1),
                                          __high2float(w2), __high2float(w3));
            *reinterpret_cast<float4*>(fy + (size_t)t * D)       = lo;
            *reinterpret_cast<float4*>(fy + (size_t)(t + 1) * D) = hi;
        }
    }
}

} // namespace

extern "C" void kernel_launch(void* const* d_in, const int* in_sizes, int n_in,
                              void* d_out, int out_size, void* d_ws, size_t ws_size,
                              hipStream_t stream) {
    const float* x  = (const float*)d_in[0];
    const float* h0 = (const float*)d_in[1];
    const float* h1 = (const float*)d_in[2];
    const float* w  = (const float*)d_in[3];
    float* y = (float*)d_out;
    (void)d_ws; (void)ws_size;

    const int B = in_sizes[0] / (L * D);   // = 8

    dim3 g1((L + K1_OUT - 1) / K1_OUT, D / CT, B);  // (43, 8, 8)
    dim3 g2(32, D / CT, B);                          // (32, 8, 8): t2 pairs

    mrl_k1<<<g1, 512, 0, stream>>>(x, h0, h1, w, (uint32_t*)y);
    mrl_k2<<<g2, 512, 0, stream>>>(h0, h1, w, y);
}